// Round 2
// baseline (427.772 us; speedup 1.0000x reference)
//
#include <hip/hip_runtime.h>
#include <stdint.h>

// QuantizedLinear: B=4, S=2048, IN=4096, OUT=4096, OUTLIER=128
// Unified int8 path:
//   W8[o,i] = round(w[o, invp[i]] / w_s_o),  w[o,:] = [qw*alpha | fpw] permuted
//   w_s_o   = rowabsmax(w[o,:]) / 127        (per-output-row scale)
//   A8[m,i] = round(A[m,i] / s_m),  s_m = rowabsmax / 127
//   out[m,o] = s_m * w_s_o * (A8 . W8^T)[m,o] + bias[o]
#define IN_F  4096
#define OUT_F 4096
#define OUTL  128
#define QIN   (IN_F - OUTL)   // 3968
#define MTOT  8192            // B*S
#define BM 128
#define BN 128
#define BKB 128               // K-bytes per LDS row per K-tile
#define NKT (IN_F / BKB)      // 32 K-tiles

typedef unsigned short u16;
typedef int i32x4  __attribute__((ext_vector_type(4)));
typedef int i32x16 __attribute__((ext_vector_type(16)));

// ---------------------------------------------------------------------------
// Fused prep. Blocks [0, OUT_F): weight rows. Blocks [OUT_F, OUT_F+MTOT):
// activation rows. All global reads coalesced float4; stores coalesced 16B.
// Weight gather LDS is PADDED (addr = j + (j>>4)): unpadded, lane l of the
// gather hits bank (16l)%32 -> 32-way conflict; pad makes lane stride 17
// (coprime with 32) -> conflict-free.
// ---------------------------------------------------------------------------
__global__ __launch_bounds__(256) void prep_fused(
    const float* __restrict__ A, signed char* __restrict__ A8,
    float* __restrict__ s_arr,
    const float* __restrict__ qw, const float* __restrict__ fpw,
    const float* __restrict__ alpha, const int* __restrict__ invp,
    signed char* __restrict__ W8, float* __restrict__ t_arr) {
  const int tid = threadIdx.x;
  __shared__ float red[4];

  if (blockIdx.x >= OUT_F) {
    // ---- activation row: absmax -> s_m, quantize to int8 ----
    const int m = blockIdx.x - OUT_F;
    const float* row = A + (size_t)m * IN_F;
    float4 v[4];
    float amax = 0.f;
#pragma unroll
    for (int k = 0; k < 4; ++k) {
      v[k] = ((const float4*)row)[k * 256 + tid];
      amax = fmaxf(amax, fmaxf(fmaxf(fabsf(v[k].x), fabsf(v[k].y)),
                               fmaxf(fabsf(v[k].z), fabsf(v[k].w))));
    }
#pragma unroll
    for (int off = 32; off; off >>= 1)
      amax = fmaxf(amax, __shfl_xor(amax, off, 64));
    if ((tid & 63) == 0) red[tid >> 6] = amax;
    __syncthreads();
    amax = fmaxf(fmaxf(red[0], red[1]), fmaxf(red[2], red[3]));
    const float inv = 127.f / amax;
    if (tid == 0) s_arr[m] = amax / 127.f;
#pragma unroll
    for (int k = 0; k < 4; ++k) {
      const int q0 = __float2int_rn(v[k].x * inv);
      const int q1 = __float2int_rn(v[k].y * inv);
      const int q2 = __float2int_rn(v[k].z * inv);
      const int q3 = __float2int_rn(v[k].w * inv);
      const uint32_t p = (q0 & 255) | ((q1 & 255) << 8) |
                         ((q2 & 255) << 16) | ((uint32_t)(q3 & 255) << 24);
      ((uint32_t*)A8)[(size_t)m * (IN_F / 4) + k * 256 + tid] = p;
    }
  } else {
    // ---- weight row: stage qw/fpw in LDS (padded), rowabsmax of
    //      [qw*a | fpw], permuted gather, quantize to int8 ----
    const int o = blockIdx.x;
    __shared__ float qs[QIN + (QIN >> 4)];  // 4216 floats, padded layout
    __shared__ float fs[OUTL];
    const float a = alpha[o];
    float amax = 0.f;
    const float4* qrow = (const float4*)(qw + (size_t)o * QIN);
#pragma unroll
    for (int k = 0; k < 4; ++k) {
      const int idx = k * 256 + tid;
      if (idx < QIN / 4) {
        const float4 q = qrow[idx];
        // padded addr of j=4*idx is 4*idx + (idx>>2); all 4 elems stay in
        // the same 16-float pad block (4*idx % 16 in {0,4,8,12}).
        const int b0 = idx * 4 + (idx >> 2);
        qs[b0]     = q.x;
        qs[b0 + 1] = q.y;
        qs[b0 + 2] = q.z;
        qs[b0 + 3] = q.w;
        const float qm = fmaxf(fmaxf(fabsf(q.x), fabsf(q.y)),
                               fmaxf(fabsf(q.z), fabsf(q.w)));
        amax = fmaxf(amax, qm * a);
      }
    }
    if (tid < OUTL / 4) {
      const float4 f = ((const float4*)(fpw + (size_t)o * OUTL))[tid];
      ((float4*)fs)[tid] = f;
      amax = fmaxf(amax, fmaxf(fmaxf(fabsf(f.x), fabsf(f.y)),
                               fmaxf(fabsf(f.z), fabsf(f.w))));
    }
    // Hoist permutation loads: issue before the reduce so the global-load
    // latency hides under the shfl chain + barrier.
    int4 jj[4];
#pragma unroll
    for (int q = 0; q < 4; ++q) jj[q] = ((const int4*)invp)[tid * 4 + q];
#pragma unroll
    for (int off = 32; off; off >>= 1)
      amax = fmaxf(amax, __shfl_xor(amax, off, 64));
    if ((tid & 63) == 0) red[tid >> 6] = amax;
    __syncthreads();  // also covers qs/fs visibility
    amax = fmaxf(fmaxf(red[0], red[1]), fmaxf(red[2], red[3]));
    const float invws = 127.f / amax;
    if (tid == 0) t_arr[o] = amax / 127.f;

    signed char vals[16];
#pragma unroll
    for (int q = 0; q < 4; ++q) {
      const int j[4] = {jj[q].x, jj[q].y, jj[q].z, jj[q].w};
#pragma unroll
      for (int e = 0; e < 4; ++e) {
        const int je = j[e];
        const float v = (je < QIN) ? qs[je + (je >> 4)] * a : fs[je - QIN];
        vals[q * 4 + e] = (signed char)__float2int_rn(v * invws);
      }
    }
    ((uint4*)(W8 + (size_t)o * IN_F))[tid] = *(const uint4*)vals;
  }
}

// ---------------------------------------------------------------------------
// GEMM: round-0 proven structure (128x128 tile, 4 waves, 32 KB LDS,
// 2 x __syncthreads per K-tile, 3 blocks/CU) upgraded to 32x32x32 i8 MFMA
// (ceiling 4404 vs 3944 TOPS) with 2x2 fragment reuse: 16 ds_read_b128 per
// K-tile per wave (was 24) and 16 MFMAs (was 32, same math).
//
// LDS layout (unchanged, measured 0 bank conflicts): row r holds 8 x 16B
// chunks; slot s stores global chunk s^(r&7), achieved by pre-swizzling the
// per-lane GLOBAL address (GLDS LDS dest must stay linear). Fragment read
// of chunk c: slot c^(r&7); within any 16-lane group banks are 2-way
// aliased (free, m136).
//
// A/B fragment layout (32x32x32 i8): row (A) / col (B) = lane&31,
// k = (lane>>5)*16 + e -> one 16B chunk per lane. C/D: col = lane&31,
// row = (reg&3) + 8*(reg>>2) + 4*(lane>>5)  [guide §3, dtype-independent].
// ---------------------------------------------------------------------------
#define GLDS(g, l)                                                              \
  __builtin_amdgcn_global_load_lds(                                             \
      (const __attribute__((address_space(1))) void*)(g),                       \
      (__attribute__((address_space(3))) void*)(l), 16, 0, 0)

__global__ __launch_bounds__(256, 3) void gemm_i8(
    const signed char* __restrict__ A8, const signed char* __restrict__ W8,
    const float* __restrict__ s_arr, const float* __restrict__ t_arr,
    const float* __restrict__ bias, float* __restrict__ C) {
  __shared__ unsigned char As8[BM * BKB];  // 16 KB
  __shared__ unsigned char Bs8[BN * BKB];  // 16 KB

  const int tid  = threadIdx.x;
  const int wave = tid >> 6;
  const int lane = tid & 63;

  // XCD-aware bijective swizzle (2048 % 8 == 0): each XCD gets 256
  // consecutive swizzled ids = 8 bm-rows x all 32 bn -> A-panel L2 reuse.
  const int bid = ((blockIdx.x & 7) << 8) | ((int)blockIdx.x >> 3);
  const int bm = bid >> 5;   // 0..63
  const int bn = bid & 31;   // 0..31

  const int wm = (wave >> 1) * 64;
  const int wn = (wave & 1)  * 64;

  // Staging: lane l -> row (l>>3) within an 8-row group, chunk (l&7) XOR'd by
  // row so LDS slot s of row r holds global chunk s^(r&7). Each GLDS covers
  // 8 rows x 128 B = 1 KB; 4 insts per tile per wave.
  const int srow   = wave * 32 + (lane >> 3);
  const int schunk = (lane & 7) ^ ((lane >> 3) & 7);
  const signed char* Ag = A8 + (size_t)(bm * BM + srow) * IN_F + schunk * 16;
  const signed char* Wg = W8 + (size_t)(bn * BN + srow) * IN_F + schunk * 16;
  unsigned char* AsW = As8 + wave * 32 * BKB;
  unsigned char* BsW = Bs8 + wave * 32 * BKB;

  i32x16 acc[2][2];
#pragma unroll
  for (int mi = 0; mi < 2; ++mi)
#pragma unroll
    for (int ni = 0; ni < 2; ++ni)
#pragma unroll
      for (int e = 0; e < 16; ++e) acc[mi][ni][e] = 0;

  const int fr = lane & 31;  // fragment row (m for A, n for B)
  const int fh = lane >> 5;  // k-half: 16B chunk within 32B k-step

  // Precomputed per-fragment row base offsets and per-k-step chunk offsets.
  int aoff[2], boff[2], ck[4];
#pragma unroll
  for (int mi = 0; mi < 2; ++mi) aoff[mi] = (wm + mi * 32 + fr) * BKB;
#pragma unroll
  for (int ni = 0; ni < 2; ++ni) boff[ni] = (wn + ni * 32 + fr) * BKB;
#pragma unroll
  for (int ks = 0; ks < 4; ++ks) ck[ks] = (((ks * 2 + fh) ^ (fr & 7)) * 16);

  for (int kt = 0; kt < NKT; ++kt) {  // 32 iterations
    __syncthreads();
#pragma unroll
    for (int t = 0; t < 4; ++t) {
      GLDS(Ag + kt * BKB + t * 8 * IN_F, AsW + t * 8 * BKB);
      GLDS(Wg + kt * BKB + t * 8 * IN_F, BsW + t * 8 * BKB);
    }
    __syncthreads();

#pragma unroll
    for (int ks = 0; ks < 4; ++ks) {
      i32x4 af[2], bg[2];
#pragma unroll
      for (int mi = 0; mi < 2; ++mi)
        af[mi] = *(const i32x4*)&As8[aoff[mi] + ck[ks]];
#pragma unroll
      for (int ni = 0; ni < 2; ++ni)
        bg[ni] = *(const i32x4*)&Bs8[boff[ni] + ck[ks]];
#pragma unroll
      for (int mi = 0; mi < 2; ++mi)
#pragma unroll
        for (int ni = 0; ni < 2; ++ni)
          acc[mi][ni] = __builtin_amdgcn_mfma_i32_32x32x32_i8(
              af[mi], bg[ni], acc[mi][ni], 0, 0, 0);
    }
  }

  // Epilogue. C/D 32x32 layout: col = lane&31 (n),
  // row = (reg&3) + 8*(reg>>2) + 4*(lane>>5) (m).
  float sv[2][16];
#pragma unroll
  for (int mi = 0; mi < 2; ++mi)
#pragma unroll
    for (int r = 0; r < 16; ++r)
      sv[mi][r] =
          s_arr[bm * BM + wm + mi * 32 + (r & 3) + 8 * (r >> 2) + 4 * fh];

#pragma unroll
  for (int ni = 0; ni < 2; ++ni) {
    const int n = bn * BN + wn + ni * 32 + fr;
    const float tn = t_arr[n];
    const float bv = bias[n];
#pragma unroll
    for (int mi = 0; mi < 2; ++mi) {
      const int m0 = bm * BM + wm + mi * 32 + 4 * fh;
#pragma unroll
      for (int r = 0; r < 16; ++r) {
        const int m = m0 + (r & 3) + 8 * (r >> 2);
        C[(size_t)m * OUT_F + n] = (float)acc[mi][ni][r] * (sv[mi][r] * tn) + bv;
      }
    }
  }
}

extern "C" void kernel_launch(void* const* d_in, const int* in_sizes, int n_in,
                              void* d_out, int out_size, void* d_ws, size_t ws_size,
                              hipStream_t stream) {
  const float* input = (const float*)d_in[0];  // (4,2048,4096) fp32
  const float* qw    = (const float*)d_in[1];  // (4096,3968) fp32
  const float* fpw   = (const float*)d_in[2];  // (4096,128) fp32
  const float* alpha = (const float*)d_in[3];  // (4096,1) fp32
  const float* bias  = (const float*)d_in[4];  // (4096,) fp32
  const int*   invp  = (const int*)d_in[5];    // (4096,) int32

  char* ws = (char*)d_ws;
  signed char* A8    = (signed char*)ws;                        // 32 MB
  signed char* W8    = (signed char*)(ws + (32ull << 20));      // 16 MB
  float* s_arr = (float*)(ws + (48ull << 20));                  // 32 KB
  float* t_arr = (float*)(ws + (48ull << 20) + (64ull << 10));  // 16 KB
  float* out = (float*)d_out;

  prep_fused<<<OUT_F + MTOT, 256, 0, stream>>>(input, A8, s_arr, qw, fpw,
                                               alpha, invp, W8, t_arr);

  gemm_i8<<<dim3((MTOT / BM) * (OUT_F / BN)), dim3(256), 0, stream>>>(
      A8, W8, s_arr, t_arr, bias, out);
}

// Round 3
// 397.855 us; speedup vs baseline: 1.0752x; 1.0752x over previous
//
#include <hip/hip_runtime.h>
#include <stdint.h>

// QuantizedLinear: B=4, S=2048, IN=4096, OUT=4096, OUTLIER=128
// Unified int8 path:
//   W8[o,i] = round(w[o, invp[i]] / w_s_o),  w[o,:] = [qw*alpha | fpw] permuted
//   w_s_o   = rowabsmax(w[o,:]) / 127        (per-output-row scale)
//   A8[m,i] = round(A[m,i] / s_m),  s_m = rowabsmax / 127
//   out[m,o] = s_m * w_s_o * (A8 . W8^T)[m,o] + bias[o]
#define IN_F  4096
#define OUT_F 4096
#define OUTL  128
#define QIN   (IN_F - OUTL)   // 3968
#define MTOT  8192            // B*S
#define BM 128
#define BN 128
#define BKB 128               // K-bytes per LDS row per iteration

typedef unsigned short u16;
typedef int i32x4 __attribute__((ext_vector_type(4)));

// Padded LDS address for the weight gather: +4 floats per 32.
// Gather sources je are near-consecutive (je ~ 16*lane + c), so padded lane
// stride ~18 mod 32 -> <=2-way bank alias (free, m136). Unpadded would be
// 16*lane -> 2 banks for 64 lanes (32-way). Pad of 4 keeps float4 stores
// aligned (vs +1-per-16 which forces scalar stores).
#define QPAD(j) ((j) + (((j) >> 5) << 2))

// ---------------------------------------------------------------------------
// Fused prep. Blocks [0, OUT_F): weight rows. Blocks [OUT_F, OUT_F+MTOT):
// activation rows. All global reads coalesced float4; stores coalesced 16B.
// ---------------------------------------------------------------------------
__global__ __launch_bounds__(256) void prep_fused(
    const float* __restrict__ A, signed char* __restrict__ A8,
    float* __restrict__ s_arr,
    const float* __restrict__ qw, const float* __restrict__ fpw,
    const float* __restrict__ alpha, const int* __restrict__ invp,
    signed char* __restrict__ W8, float* __restrict__ t_arr) {
  const int tid = threadIdx.x;
  __shared__ float red[4];

  if (blockIdx.x >= OUT_F) {
    // ---- activation row: absmax -> s_m, quantize to int8 ----
    const int m = blockIdx.x - OUT_F;
    const float* row = A + (size_t)m * IN_F;
    float4 v[4];
    float amax = 0.f;
#pragma unroll
    for (int k = 0; k < 4; ++k) {
      v[k] = ((const float4*)row)[k * 256 + tid];
      amax = fmaxf(amax, fmaxf(fmaxf(fabsf(v[k].x), fabsf(v[k].y)),
                               fmaxf(fabsf(v[k].z), fabsf(v[k].w))));
    }
#pragma unroll
    for (int off = 32; off; off >>= 1)
      amax = fmaxf(amax, __shfl_xor(amax, off, 64));
    if ((tid & 63) == 0) red[tid >> 6] = amax;
    __syncthreads();
    amax = fmaxf(fmaxf(red[0], red[1]), fmaxf(red[2], red[3]));
    const float inv = 127.f / amax;
    if (tid == 0) s_arr[m] = amax / 127.f;
#pragma unroll
    for (int k = 0; k < 4; ++k) {
      const int q0 = __float2int_rn(v[k].x * inv);
      const int q1 = __float2int_rn(v[k].y * inv);
      const int q2 = __float2int_rn(v[k].z * inv);
      const int q3 = __float2int_rn(v[k].w * inv);
      const uint32_t p = (q0 & 255) | ((q1 & 255) << 8) |
                         ((q2 & 255) << 16) | ((uint32_t)(q3 & 255) << 24);
      ((uint32_t*)A8)[(size_t)m * (IN_F / 4) + k * 256 + tid] = p;
    }
  } else {
    // ---- weight row: stage qw/fpw in LDS (padded), rowabsmax of
    //      [qw*a | fpw], permuted gather, quantize to int8 ----
    const int o = blockIdx.x;
    __shared__ float qs[QIN + ((QIN >> 5) << 2)];  // 4464 floats, padded
    __shared__ float fs[OUTL];

    // Hoist latency-critical loads: invp (consumed last, issue first so the
    // ~600cy global latency hides under everything), then fpw, then qw.
    int4 jj[4];
#pragma unroll
    for (int q = 0; q < 4; ++q) jj[q] = ((const int4*)invp)[tid * 4 + q];

    const float a = alpha[o];
    float amax = 0.f;

    float4 f;
    if (tid < OUTL / 4) f = ((const float4*)(fpw + (size_t)o * OUTL))[tid];

    const float4* qrow = (const float4*)(qw + (size_t)o * QIN);
#pragma unroll
    for (int k = 0; k < 4; ++k) {
      const int idx = k * 256 + tid;
      if (idx < QIN / 4) {
        const float4 q = qrow[idx];
        // padded float4 store: j = 4*idx -> b0 = 4*idx + ((idx>>3)<<2);
        // all 4 elems stay within one 32-float pad block, 16B-aligned.
        ((float4*)&qs[idx * 4 + ((idx >> 3) << 2)])[0] = q;
        const float qm = fmaxf(fmaxf(fabsf(q.x), fabsf(q.y)),
                               fmaxf(fabsf(q.z), fabsf(q.w)));
        amax = fmaxf(amax, qm * a);
      }
    }
    if (tid < OUTL / 4) {
      ((float4*)fs)[tid] = f;
      amax = fmaxf(amax, fmaxf(fmaxf(fabsf(f.x), fabsf(f.y)),
                               fmaxf(fabsf(f.z), fabsf(f.w))));
    }
#pragma unroll
    for (int off = 32; off; off >>= 1)
      amax = fmaxf(amax, __shfl_xor(amax, off, 64));
    if ((tid & 63) == 0) red[tid >> 6] = amax;
    __syncthreads();  // also covers qs/fs visibility
    amax = fmaxf(fmaxf(red[0], red[1]), fmaxf(red[2], red[3]));
    const float invws = 127.f / amax;
    if (tid == 0) t_arr[o] = amax / 127.f;

    signed char vals[16];
#pragma unroll
    for (int q = 0; q < 4; ++q) {
      const int j[4] = {jj[q].x, jj[q].y, jj[q].z, jj[q].w};
#pragma unroll
      for (int e = 0; e < 4; ++e) {
        const int je = j[e];
        const float v = (je < QIN) ? qs[QPAD(je)] * a : fs[je - QIN];
        vals[q * 4 + e] = (signed char)__float2int_rn(v * invws);
      }
    }
    ((uint4*)(W8 + (size_t)o * IN_F))[tid] = *(const uint4*)vals;
  }
}

// ---------------------------------------------------------------------------
// GEMM: round-0 proven structure, byte-for-byte. Single i8 K=4096 loop,
// BK=128 bytes/row (32 iters). 128x128 tile, 4 waves, 32 KB LDS, 3 blocks/CU.
// Measured: 141.8 us, MfmaUtil 46.6, SQ_LDS_BANK_CONFLICT = 0.
//
// NO XCD swizzle and 2D grid with bn = blockIdx.x fast-varying: the default
// round-robin dispatch gives each XCD bn = x mod 8 -> a 2 MB W8 slice that
// fits its private L2 (measured round 2: chunked swizzle doubled FETCH).
//
// LDS layout (measured 0 conflicts): row r holds 8 x 16B chunks; slot c^(r&7)
// holds global chunk c, via pre-swizzled per-lane GLOBAL address (GLDS LDS
// dest must stay linear). 16x16 fragment reads are conflict-free; the 32x32
// pattern on this layout measured 4 extra cycles per b128 (round 2) - do not
// switch MFMA shape on this layout.
// ---------------------------------------------------------------------------
#define GLDS(g, l)                                                              \
  __builtin_amdgcn_global_load_lds(                                             \
      (const __attribute__((address_space(1))) void*)(g),                       \
      (__attribute__((address_space(3))) void*)(l), 16, 0, 0)

__global__ __launch_bounds__(256, 3) void gemm_i8(
    const signed char* __restrict__ A8, const signed char* __restrict__ W8,
    const float* __restrict__ s_arr, const float* __restrict__ t_arr,
    const float* __restrict__ bias, float* __restrict__ C) {
  __shared__ unsigned char As8[BM * BKB];  // 16 KB
  __shared__ unsigned char Bs8[BN * BKB];  // 16 KB

  const int tid  = threadIdx.x;
  const int wave = tid >> 6;
  const int lane = tid & 63;
  const int bn = blockIdx.x, bm = blockIdx.y;
  const int wm = (wave >> 1) * 64;
  const int wn = (wave & 1)  * 64;

  // Staging: lane l -> row (l>>3) within an 8-row group, chunk (l&7) XOR'd by
  // row so LDS slot s of row r holds global chunk s^(r&7). Each GLDS covers
  // 8 rows x 128 B = 1 KB; 4 insts per tile per wave.
  const int srow   = wave * 32 + (lane >> 3);
  const int schunk = (lane & 7) ^ ((lane >> 3) & 7);
  const signed char* Ag = A8 + (size_t)(bm * BM + srow) * IN_F + schunk * 16;
  const signed char* Wg = W8 + (size_t)(bn * BN + srow) * IN_F + schunk * 16;
  unsigned char* AsW = As8 + wave * 32 * BKB;
  unsigned char* BsW = Bs8 + wave * 32 * BKB;

  i32x4 acc[4][4];
#pragma unroll
  for (int mi = 0; mi < 4; ++mi)
#pragma unroll
    for (int ni = 0; ni < 4; ++ni) acc[mi][ni] = (i32x4){0, 0, 0, 0};

  const int fr = lane & 15;  // fragment row (m for A, n for B)
  const int fq = lane >> 4;  // quad -> 16B k-chunk within 64B k-step

  for (int kt = 0; kt < IN_F / BKB; ++kt) {  // 32 iterations
    __syncthreads();
#pragma unroll
    for (int t = 0; t < 4; ++t) {
      GLDS(Ag + kt * BKB + t * 8 * IN_F, AsW + t * 8 * BKB);
      GLDS(Wg + kt * BKB + t * 8 * IN_F, BsW + t * 8 * BKB);
    }
    __syncthreads();

#pragma unroll
    for (int ks = 0; ks < 2; ++ks) {
      i32x4 af[4], bg[4];
#pragma unroll
      for (int mi = 0; mi < 4; ++mi)
        af[mi] = *(const i32x4*)
            &As8[(wm + mi * 16 + fr) * BKB + (((ks * 4 + fq) ^ (fr & 7)) * 16)];
#pragma unroll
      for (int ni = 0; ni < 4; ++ni)
        bg[ni] = *(const i32x4*)
            &Bs8[(wn + ni * 16 + fr) * BKB + (((ks * 4 + fq) ^ (fr & 7)) * 16)];
#pragma unroll
      for (int mi = 0; mi < 4; ++mi)
#pragma unroll
        for (int ni = 0; ni < 4; ++ni)
          acc[mi][ni] = __builtin_amdgcn_mfma_i32_16x16x64_i8(
              af[mi], bg[ni], acc[mi][ni], 0, 0, 0);
    }
  }

  // Epilogue: C/D layout col = lane&15 (n), row = (lane>>4)*4 + reg (m).
  float sv[4][4];
#pragma unroll
  for (int mi = 0; mi < 4; ++mi)
#pragma unroll
    for (int rr = 0; rr < 4; ++rr)
      sv[mi][rr] = s_arr[bm * BM + wm + mi * 16 + fq * 4 + rr];

#pragma unroll
  for (int ni = 0; ni < 4; ++ni) {
    const int n = bn * BN + wn + ni * 16 + fr;
    const float tn = t_arr[n];
    const float bv = bias[n];
#pragma unroll
    for (int mi = 0; mi < 4; ++mi) {
      const int m0 = bm * BM + wm + mi * 16 + fq * 4;
#pragma unroll
      for (int rr = 0; rr < 4; ++rr)
        C[(size_t)(m0 + rr) * OUT_F + n] =
            (float)acc[mi][ni][rr] * (sv[mi][rr] * tn) + bv;
    }
  }
}

extern "C" void kernel_launch(void* const* d_in, const int* in_sizes, int n_in,
                              void* d_out, int out_size, void* d_ws, size_t ws_size,
                              hipStream_t stream) {
  const float* input = (const float*)d_in[0];  // (4,2048,4096) fp32
  const float* qw    = (const float*)d_in[1];  // (4096,3968) fp32
  const float* fpw   = (const float*)d_in[2];  // (4096,128) fp32
  const float* alpha = (const float*)d_in[3];  // (4096,1) fp32
  const float* bias  = (const float*)d_in[4];  // (4096,) fp32
  const int*   invp  = (const int*)d_in[5];    // (4096,) int32

  char* ws = (char*)d_ws;
  signed char* A8    = (signed char*)ws;                        // 32 MB
  signed char* W8    = (signed char*)(ws + (32ull << 20));      // 16 MB
  float* s_arr = (float*)(ws + (48ull << 20));                  // 32 KB
  float* t_arr = (float*)(ws + (48ull << 20) + (64ull << 10));  // 16 KB
  float* out = (float*)d_out;

  prep_fused<<<OUT_F + MTOT, 256, 0, stream>>>(input, A8, s_arr, qw, fpw,
                                               alpha, invp, W8, t_arr);

  dim3 ggrid(OUT_F / BN, MTOT / BM);  // (32, 64)
  gemm_i8<<<ggrid, dim3(256), 0, stream>>>(A8, W8, s_arr, t_arr, bias, out);
}